// Round 7
// baseline (313.659 us; speedup 1.0000x reference)
//
#include <hip/hip_runtime.h>
#include <hip/hip_bf16.h>
#include <math.h>

typedef __bf16 bf16;
typedef __bf16 bf16x4 __attribute__((ext_vector_type(4)));
typedef __bf16 bf16x8 __attribute__((ext_vector_type(8)));
typedef float f32x4 __attribute__((ext_vector_type(4)));

#define OCC 230
#define NRELS 53
// ws bf16-elem offsets
#define W2V48_OFF 0        // 50000 x 48 (dims 0..47)
#define WTAIL_OFF 2400000  // 50000 x 2  (d48,d49) dword-packed
#define PCAT_OFF  2500000  // 3721 x 16: [p1_0..4, p2_0, 0, 0 | p2_1..4, 0,0,0,0]
#define REMBB_OFF 2559552  // 64 x 768 (col = p*256+oc; oc>=230 or rel>=53 -> 0)
#define CONVB_OFF 2608704  // 256 x 192 (k>=180 or oc>=230 -> 0)
#define FLWS_OFF  2657862  // 8000 x 768 bf16 tanh features
// total ~8.80M bf16 elems = 17.6 MB

union FragU { bf16x8 v8; bf16x4 v4[2]; bf16 e[8]; };

// ---- prep: build bf16 tables ----
__global__ void pcnn_prep(const float* __restrict__ w2v, const float* __restrict__ p1e,
                          const float* __restrict__ p2e, const float* __restrict__ remb,
                          const float* __restrict__ convw, bf16* __restrict__ wsb) {
  const int i = blockIdx.x * 256 + threadIdx.x;
  if (i < 300000) {                       // w2v48: 8 elems/thread, vectorized
    const int w = i / 6, c = i - 6 * w;
    const float2* s = reinterpret_cast<const float2*>(w2v + w * 50 + c * 8);
    const float2 f0 = s[0], f1 = s[1], f2 = s[2], f3 = s[3];
    bf16x8 v = {(bf16)f0.x, (bf16)f0.y, (bf16)f1.x, (bf16)f1.y,
                (bf16)f2.x, (bf16)f2.y, (bf16)f3.x, (bf16)f3.y};
    *reinterpret_cast<bf16x8*>(wsb + W2V48_OFF + w * 48 + c * 8) = v;
    return;
  }
  int e = i - 300000;
  if (e < 50000) {                        // wtail: (d48,d49)
    const float2 f = *reinterpret_cast<const float2*>(w2v + e * 50 + 48);
    wsb[WTAIL_OFF + 2 * e]     = (bf16)f.x;
    wsb[WTAIL_OFF + 2 * e + 1] = (bf16)f.y;
    return;
  }
  e -= 50000;
  if (e < 7442) {                         // pcat16 halves
    const int row = e >> 1, h = e & 1;
    const int v1 = row / 61, v2 = row - v1 * 61;
    bf16x8 v;
    if (h == 0) {
      v[0] = (bf16)p1e[v1 * 5 + 0]; v[1] = (bf16)p1e[v1 * 5 + 1];
      v[2] = (bf16)p1e[v1 * 5 + 2]; v[3] = (bf16)p1e[v1 * 5 + 3];
      v[4] = (bf16)p1e[v1 * 5 + 4]; v[5] = (bf16)p2e[v2 * 5 + 0];
      v[6] = (bf16)0.f; v[7] = (bf16)0.f;
    } else {
      v[0] = (bf16)p2e[v2 * 5 + 1]; v[1] = (bf16)p2e[v2 * 5 + 2];
      v[2] = (bf16)p2e[v2 * 5 + 3]; v[3] = (bf16)p2e[v2 * 5 + 4];
      v[4] = (bf16)0.f; v[5] = (bf16)0.f; v[6] = (bf16)0.f; v[7] = (bf16)0.f;
    }
    *reinterpret_cast<bf16x8*>(wsb + PCAT_OFF + row * 16 + h * 8) = v;
    return;
  }
  e -= 7442;
  if (e < 6144) {                         // rembb [64][768]
    const int r = e / 96, c0 = (e - r * 96) * 8;
    bf16x8 v;
#pragma unroll
    for (int j = 0; j < 8; ++j) {
      const int cc = c0 + j, p = cc >> 8, oc = cc & 255;
      v[j] = (r < NRELS && oc < OCC) ? (bf16)remb[r * 690 + p * OCC + oc] : (bf16)0.f;
    }
    *reinterpret_cast<bf16x8*>(wsb + REMBB_OFF + r * 768 + c0) = v;
    return;
  }
  e -= 6144;
  if (e < 6144) {                         // convb [256][192]
    const int oc = e / 24, k0 = (e - oc * 24) * 8;
    bf16x8 v;
#pragma unroll
    for (int j = 0; j < 8; ++j) {
      const int k = k0 + j;
      v[j] = (oc < OCC && k < 180) ? (bf16)convw[oc * 180 + k] : (bf16)0.f;
    }
    *reinterpret_cast<bf16x8*>(wsb + CONVB_OFF + oc * 192 + k0) = v;
  }
}

// ---- K1: conv+pool+tanh, one (sentence, oc-half) per 256-thr block ----
#define XE 7352   // 122 rows x 60 elems + pad (max read 119*60+191+1 = 7332)

__global__ __launch_bounds__(256, 3)
void pcnn_conv(const int* __restrict__ words, const int* __restrict__ posi,
               const float* __restrict__ cb0, const float* __restrict__ cb1,
               const float* __restrict__ cb2, const bf16* __restrict__ wsb,
               bf16* __restrict__ flws)
{
  __shared__ __align__(16) bf16 xlds[XE];   // A[m][k] = xlds[m*60+k]; LDS row l+1 = x row l
  __shared__ int widx[120];

  const int t = threadIdx.x;
  const int bid = blockIdx.x;
  const int ns = bid >> 1;       // sentence id 0..7999
  const int ochalf = bid & 1;
  const int wv = t >> 6, lane = t & 63, g = lane >> 4, cl = lane & 15;

  if (t < 120) {
    const int w = words[ns * 120 + t];
    const int2 pp = *reinterpret_cast<const int2*>(posi + ns * 240 + 2 * t);
    const bool b0 = pp.x >= 30, b1 = pp.y >= 30;
    const int pc = (b0 && b1) ? 0 : ((!b0 && !b1) ? 2 : 1);
    widx[t] = w | ((pp.x * 61 + pp.y) << 16) | (pc << 28);
  }
  // zero pad rows (LDS rows 0 and 121)
  if (t < 16) {
    const int r = (t >> 3) ? 121 : 0;
    const int gr = t & 7;
    const int eo = r * 60 + ((gr < 7) ? gr * 8 : 52);
    *reinterpret_cast<int2*>(&xlds[eo])     = int2{0, 0};
    *reinterpret_cast<int2*>(&xlds[eo + 4]) = int2{0, 0};
  }

  // conv weights -> regs (oc-half selected by block)
  FragU Bf[2][6];
  {
    const bf16* cwb = wsb + CONVB_OFF;
#pragma unroll
    for (int nt = 0; nt < 2; ++nt) {
      const int oc = ochalf * 128 + wv * 32 + nt * 16 + cl;
#pragma unroll
      for (int ks = 0; ks < 6; ++ks)
        Bf[nt][ks].v8 = *reinterpret_cast<const bf16x8*>(cwb + oc * 192 + ks * 32 + g * 8);
    }
  }
  __syncthreads();  // widx ready

  // reg-staged gather: 960 granules (8 per x-row), 16B loads -> 8B LDS writes
#pragma unroll
  for (int k = 0; k < 4; ++k) {
    const int gi = t + k * 256;
    if (gi < 960) {
      const int lr = 1 + (gi >> 3), gr = gi & 7;
      const int wi = widx[lr - 1];
      const int word = wi & 0xFFFF;
      const int pidx = (wi >> 16) & 0xFFF;
      if (gr < 6) {
        const int4 v = *reinterpret_cast<const int4*>(wsb + W2V48_OFF + word * 48 + gr * 8);
        bf16* d = &xlds[lr * 60 + gr * 8];
        *reinterpret_cast<int2*>(d)     = int2{v.x, v.y};
        *reinterpret_cast<int2*>(d + 4) = int2{v.z, v.w};
      } else if (gr == 6) {   // elems 48..55 = [d48,d49,p1_0..4,p2_0]
        const int wt = *(reinterpret_cast<const int*>(wsb + WTAIL_OFF) + word);
        const int4 pc4 = *reinterpret_cast<const int4*>(wsb + PCAT_OFF + pidx * 16);
        bf16* d = &xlds[lr * 60 + 48];
        *reinterpret_cast<int2*>(d)     = int2{wt, pc4.x};
        *reinterpret_cast<int2*>(d + 4) = int2{pc4.y, pc4.z};
      } else {                // elems 56..59 = [p2_1..4]
        const int2 v = *reinterpret_cast<const int2*>(wsb + PCAT_OFF + pidx * 16 + 8);
        *reinterpret_cast<int2*>(&xlds[lr * 60 + 56]) = v;
      }
    }
  }
  __syncthreads();  // xlds ready

  // conv GEMM: all 8 m-tiles per wave, nt=2
  int mrow[8];
#pragma unroll
  for (int mt = 0; mt < 8; ++mt) {
    const int m = mt * 16 + cl;
    mrow[mt] = (m < 120 ? m : 119) * 60;
  }

  f32x4 acc[8][2];
  const f32x4 z4 = {0.f, 0.f, 0.f, 0.f};
#pragma unroll
  for (int mt = 0; mt < 8; ++mt) { acc[mt][0] = z4; acc[mt][1] = z4; }

#pragma unroll
  for (int ks = 0; ks < 6; ++ks) {
    const int ko = ks * 32 + g * 8;
#pragma unroll
    for (int mt = 0; mt < 8; ++mt) {
      FragU a;
      a.v4[0] = *reinterpret_cast<const bf16x4*>(&xlds[mrow[mt] + ko]);
      a.v4[1] = *reinterpret_cast<const bf16x4*>(&xlds[mrow[mt] + ko + 4]);
#pragma unroll
      for (int nt = 0; nt < 2; ++nt)
        acc[mt][nt] = __builtin_amdgcn_mfma_f32_16x16x32_bf16(
            a.v8, Bf[nt][ks].v8, acc[mt][nt], 0, 0, 0);
    }
  }

  // piecewise masked max-pool (ref semantics: masked-out contributes 0)
  float pool[2][3];
#pragma unroll
  for (int nt = 0; nt < 2; ++nt) { pool[nt][0] = pool[nt][1] = pool[nt][2] = -INFINITY; }
#pragma unroll
  for (int mt = 0; mt < 8; ++mt) {
    const int l0 = mt * 16 + g * 4;
    if (l0 < 120) {
      const int4 pv = *reinterpret_cast<const int4*>(&widx[l0]);
      const int pcs[4] = {(int)((unsigned)pv.x >> 28), (int)((unsigned)pv.y >> 28),
                          (int)((unsigned)pv.z >> 28), (int)((unsigned)pv.w >> 28)};
#pragma unroll
      for (int r = 0; r < 4; ++r) {
        const int p = pcs[r];
#pragma unroll
        for (int nt = 0; nt < 2; ++nt) {
          const float v = acc[mt][nt][r];
          pool[nt][0] = fmaxf(pool[nt][0], p == 0 ? v : 0.0f);
          pool[nt][1] = fmaxf(pool[nt][1], p == 1 ? v : 0.0f);
          pool[nt][2] = fmaxf(pool[nt][2], p == 2 ? v : 0.0f);
        }
      }
    }
  }
#pragma unroll
  for (int nt = 0; nt < 2; ++nt)
#pragma unroll
    for (int p = 0; p < 3; ++p) {
      float x = pool[nt][p];
      x = fmaxf(x, __shfl_xor(x, 16));
      x = fmaxf(x, __shfl_xor(x, 32));
      pool[nt][p] = x;
    }

  if (g == 0) {
#pragma unroll
    for (int nt = 0; nt < 2; ++nt) {
      const int ocg = ochalf * 128 + wv * 32 + nt * 16 + cl;
      if (ocg < OCC) {
        const float b0v = cb0[ocg], b1v = cb1[ocg], b2v = cb2[ocg];
        bf16* fr = flws + ns * 768;
        fr[ocg]       = (bf16)tanhf(pool[nt][0] + b0v);
        fr[256 + ocg] = (bf16)tanhf(pool[nt][1] + b1v);
        fr[512 + ocg] = (bf16)tanhf(pool[nt][2] + b2v);
      }
    }
  }
}

// ---- K2: batched logits GEMM + softmax + bag-max, one bag per block ----
__global__ __launch_bounds__(256)
void pcnn_logits(const bf16* __restrict__ wsb, const bf16* __restrict__ flws,
                 const float* __restrict__ rbias, float* __restrict__ out)
{
  __shared__ __align__(16) bf16 fl_lds[6144];  // [8 sent][768]
  __shared__ float logits_l[8][64];

  const int t = threadIdx.x;
  const int bag = blockIdx.x;
  const int wv = t >> 6, lane = t & 63, g = lane >> 4, cl = lane & 15;

  // stage fl rows (linear copy via async load-to-LDS)
#pragma unroll
  for (int j = 0; j < 3; ++j) {
    const bf16* src = flws + bag * 6144 + (j * 256 + t) * 8;
    bf16* dst = &fl_lds[(j * 256 + wv * 64) * 8];
    __builtin_amdgcn_global_load_lds(
        (const __attribute__((address_space(1))) void*)src,
        (__attribute__((address_space(3))) void*)dst, 16, 0, 0);
  }
  asm volatile("s_waitcnt vmcnt(0)" ::: "memory");
  __syncthreads();

  // logits GEMM: [8 x 768] @ rembb^T[768 x 64]
  f32x4 lac = {0.f, 0.f, 0.f, 0.f};
  const bf16* brow = wsb + REMBB_OFF + (wv * 16 + cl) * 768 + g * 8;
  const bf16x8 zf = {(bf16)0.f, (bf16)0.f, (bf16)0.f, (bf16)0.f,
                     (bf16)0.f, (bf16)0.f, (bf16)0.f, (bf16)0.f};
#pragma unroll
  for (int ks = 0; ks < 24; ++ks) {
    const bf16x8 afr = (cl < 8)
        ? *reinterpret_cast<const bf16x8*>(&fl_lds[cl * 768 + ks * 32 + g * 8]) : zf;
    const bf16x8 bfr = *reinterpret_cast<const bf16x8*>(brow + ks * 32);
    lac = __builtin_amdgcn_mfma_f32_16x16x32_bf16(afr, bfr, lac, 0, 0, 0);
  }
  if (g < 2) {
    const int rel = wv * 16 + cl;
    const float bias = (rel < NRELS) ? rbias[rel] : 0.0f;
#pragma unroll
    for (int r = 0; r < 4; ++r)
      logits_l[g * 4 + r][rel] = lac[r] * 0.5f + bias;
  }
  __syncthreads();

  // softmax: wave wv handles sentences wv and wv+4
#pragma unroll
  for (int rep = 0; rep < 2; ++rep) {
    const int s = wv + rep * 4;
    const float x = (lane < NRELS) ? logits_l[s][lane] : -INFINITY;
    float m = x;
#pragma unroll
    for (int off = 32; off; off >>= 1) m = fmaxf(m, __shfl_xor(m, off));
    const float e = (lane < NRELS) ? __expf(x - m) : 0.0f;
    float sm = e;
#pragma unroll
    for (int off = 32; off; off >>= 1) sm += __shfl_xor(sm, off);
    if (lane < NRELS) logits_l[s][lane] = x - m - __logf(sm);
  }
  __syncthreads();

  if (t < NRELS) {
    float m = logits_l[0][t];
#pragma unroll
    for (int s2 = 1; s2 < 8; ++s2) m = fmaxf(m, logits_l[s2][t]);
    out[bag * NRELS + t] = m;
  }
}

extern "C" void kernel_launch(void* const* d_in, const int* in_sizes, int n_in,
                              void* d_out, int out_size, void* d_ws, size_t ws_size,
                              hipStream_t stream) {
  const int* words  = (const int*)d_in[0];
  const int* posi   = (const int*)d_in[1];
  const float* w2v  = (const float*)d_in[2];
  const float* p1e  = (const float*)d_in[3];
  const float* p2e  = (const float*)d_in[4];
  const float* cw   = (const float*)d_in[5];
  const float* cb0  = (const float*)d_in[6];
  const float* cb1  = (const float*)d_in[7];
  const float* cb2  = (const float*)d_in[8];
  const float* remb = (const float*)d_in[9];
  const float* rbias= (const float*)d_in[10];
  bf16* wsb = (bf16*)d_ws;
  bf16* flws = wsb + FLWS_OFF;
  float* out = (float*)d_out;

  pcnn_prep<<<1445, 256, 0, stream>>>(w2v, p1e, p2e, remb, cw, wsb);
  pcnn_conv<<<16000, 256, 0, stream>>>(words, posi, cb0, cb1, cb2, wsb, flws);
  pcnn_logits<<<1000, 256, 0, stream>>>(wsb, flws, rbias, out);
}